// Round 2
// baseline (11.522 us; speedup 1.0000x reference)
//
#include <hip/hip_runtime.h>

// Analytic collapse of the 4-qubit reference circuit: expz(theta) == cos(theta).
// Derivation: amp0[k] = c^(4-p)s^p (p=popcount), CNOT-chain permutation Q +
// sign on MSB reduce to (C-S)(C+S) with C=cos^2(t/2), S=sin^2(t/2) -> cos(t).
// Pure streaming map: out[i] = cos(in[i]). Memory-bound; optimize for MLP.

__global__ void __launch_bounds__(256)
QuantumLayer_65481071404620_kernel(const float4* __restrict__ in,
                                   float4* __restrict__ out,
                                   int n4) {
    const int stride = gridDim.x * blockDim.x;   // 2048*256 = 524288
    int i = blockIdx.x * blockDim.x + threadIdx.x;

    // 2x-unrolled grid-stride: issue BOTH independent loads before any use,
    // so each thread keeps 32B in flight (latency hiding at small N).
    for (; i + stride < n4; i += 2 * stride) {
        float4 a = in[i];
        float4 b = in[i + stride];
        float4 ra, rb;
        ra.x = __cosf(a.x); ra.y = __cosf(a.y);
        ra.z = __cosf(a.z); ra.w = __cosf(a.w);
        rb.x = __cosf(b.x); rb.y = __cosf(b.y);
        rb.z = __cosf(b.z); rb.w = __cosf(b.w);
        out[i] = ra;
        out[i + stride] = rb;
    }
    // remainder (at most one element per thread)
    if (i < n4) {
        float4 a = in[i];
        float4 ra;
        ra.x = __cosf(a.x); ra.y = __cosf(a.y);
        ra.z = __cosf(a.z); ra.w = __cosf(a.w);
        out[i] = ra;
    }
}

// Scalar tail (n % 4 != 0 safety; not hit for n = 4194304).
__global__ void __launch_bounds__(64)
QuantumLayer_tail_kernel(const float* __restrict__ in,
                         float* __restrict__ out,
                         int start, int n) {
    int i = start + blockIdx.x * blockDim.x + threadIdx.x;
    if (i < n) out[i] = __cosf(in[i]);
}

extern "C" void kernel_launch(void* const* d_in, const int* in_sizes, int n_in,
                              void* d_out, int out_size, void* d_ws, size_t ws_size,
                              hipStream_t stream) {
    const float* theta = (const float*)d_in[0];
    float* out = (float*)d_out;
    const int n = in_sizes[0];          // 4194304
    const int n4 = n >> 2;              // 1048576 float4s

    const int block = 256;
    int grid = (n4 + 2 * block - 1) / (2 * block);  // each thread covers 2 float4
    if (grid > 2048) grid = 2048;
    if (grid < 1) grid = 1;

    QuantumLayer_65481071404620_kernel<<<grid, block, 0, stream>>>(
        (const float4*)theta, (float4*)out, n4);

    const int tail_start = n4 << 2;
    const int tail_n = n - tail_start;
    if (tail_n > 0) {
        QuantumLayer_tail_kernel<<<(tail_n + 63) / 64, 64, 0, stream>>>(
            theta, out, tail_start, n);
    }
}

// Round 3
// 10.845 us; speedup vs baseline: 1.0625x; 1.0625x over previous
//
#include <hip/hip_runtime.h>

// Analytic collapse of the 4-qubit reference circuit: expz(theta) == cos(theta).
// Derivation: amp0[k] = c^(4-p)s^p (p=popcount), CNOT-chain permutation Q +
// sign on MSB reduce to (C-S)(C+S) with C=cos^2(t/2), S=sin^2(t/2) -> cos(t).
// Pure streaming map: out[i] = cos(in[i]); 33.5 MB total traffic.
//
// R3: max-TLP flat launch — one float4 per thread, no loop, no branches.
// 4096 blocks x 256 threads covers n4 = 1048576 exactly.

__global__ void __launch_bounds__(256)
QuantumLayer_65481071404620_kernel(const float4* __restrict__ in,
                                   float4* __restrict__ out) {
    const int i = blockIdx.x * blockDim.x + threadIdx.x;
    float4 t = in[i];
    float4 r;
    r.x = __cosf(t.x);   // v_cos_f32: |err| ~1e-5 for theta~N(0,1), thr 2e-2
    r.y = __cosf(t.y);
    r.z = __cosf(t.z);
    r.w = __cosf(t.w);
    out[i] = r;
}

// Fallback for sizes not divisible by (4 * 256) — not hit for n = 4194304.
__global__ void __launch_bounds__(256)
QuantumLayer_generic_kernel(const float* __restrict__ in,
                            float* __restrict__ out, int n) {
    int i = blockIdx.x * blockDim.x + threadIdx.x;
    if (i < n) out[i] = __cosf(in[i]);
}

extern "C" void kernel_launch(void* const* d_in, const int* in_sizes, int n_in,
                              void* d_out, int out_size, void* d_ws, size_t ws_size,
                              hipStream_t stream) {
    const float* theta = (const float*)d_in[0];
    float* out = (float*)d_out;
    const int n = in_sizes[0];          // 4194304

    const int block = 256;
    if ((n & 3) == 0 && ((n >> 2) % block) == 0) {
        const int n4 = n >> 2;          // 1048576
        QuantumLayer_65481071404620_kernel<<<n4 / block, block, 0, stream>>>(
            (const float4*)theta, (float4*)out);
    } else {
        QuantumLayer_generic_kernel<<<(n + block - 1) / block, block, 0, stream>>>(
            theta, out, n);
    }
}